// Round 14
// baseline (18389.299 us; speedup 1.0000x reference)
//
#include <hip/hip_runtime.h>
#include <hip/hip_bf16.h>

#define BB 32
#define SS 128
#define CC 128
#define HH 128
#define OO 64

typedef _Float16 f16;
typedef f16 h2 __attribute__((ext_vector_type(2)));
typedef f16 f16x8 __attribute__((ext_vector_type(8)));
typedef float f32x4 __attribute__((ext_vector_type(4)));
typedef unsigned u32x2 __attribute__((ext_vector_type(2)));
typedef unsigned u32x4 __attribute__((ext_vector_type(4)));

__device__ __forceinline__ float sigmoidf_(float x) {
    return 1.0f / (1.0f + __expf(-x));
}
__device__ __forceinline__ float tanh_fast_(float x) {
    return 1.0f - 2.0f / (__expf(2.0f * x) + 1.0f);
}
__device__ __forceinline__ unsigned pack2f(float a, float b) {
    h2 v; v[0] = (f16)a; v[1] = (f16)b;
    return __builtin_bit_cast(unsigned, v);
}
// 8 consecutive f32 -> f16x8 (element e = p[e]); the k-slot bijection is
// OURS as long as A-pack and B-layout agree (contiguous k = 8*(l>>4)+e).
__device__ __forceinline__ f16x8 packA8(const float* p) {
    u32x4 u;
    u.x = pack2f(p[0], p[1]); u.y = pack2f(p[2], p[3]);
    u.z = pack2f(p[4], p[5]); u.w = pack2f(p[6], p[7]);
    return __builtin_bit_cast(f16x8, u);
}
#define MFMA16(a, b, c) __builtin_amdgcn_mfma_f32_16x16x32_f16(a, b, c, 0, 0, 0)

// Gate math for 4 rows (one f32x4 accumulator set). C/D layout (m89-verified):
// col = lane&15 (batch), row = 4*(lane>>4) + e.
__device__ __forceinline__ f32x4 gate4(f32x4 cr, f32x4 cz, f32x4 cn,
                                       f32x4 wr, f32x4 wz, f32x4 wn,
                                       f32x4 bn, float xv, f32x4 hp) {
    f32x4 out;
    #pragma unroll
    for (int e = 0; e < 4; ++e) {
        const float r   = sigmoidf_(fmaf(xv, wr[e], cr[e]));
        const float z   = sigmoidf_(fmaf(xv, wz[e], cz[e]));
        const float gin = fmaf(xv, wn[e], bn[e]);
        const float n   = tanh_fast_(fmaf(r, cn[e], gin));
        out[e] = fmaf(z, hp[e] - n, n);            // (1-z)*n + z*h
    }
    return out;
}

// ROUND-14: MFMA-batched chains. One block = one direction x 16 batches:
// per step a 384x16x128 GEMM (24 MFMA/wave) replaces 16 separate matvecs.
// Total time = 16384 x step regardless of batching -> batching 16 chains
// into one step is the structural win over R12 (1055 cyc/step for ONE batch).
// 256 thr / wpe(1,2) / LDS>80KB = the session's only proven-resident config.
// Wave w owns gate rows {32w..32w+32} x {r,z,n}; A-frags (weights) packed
// once into 96 pinned VGPRs; B = h in LDS [16][136] f16 double-buffered;
// h carried in f32 regs; 1 barrier/step; xv loaded early / used late (L2).
__global__
__attribute__((amdgpu_flat_work_group_size(256, 256), amdgpu_waves_per_eu(1, 2)))
void gru_chain_kernel(
    const float* __restrict__ x,       // (B,S,C)
    const float* __restrict__ h_prev,  // (2,B,H)
    const float* __restrict__ Wih_f, const float* __restrict__ Whh_f,
    const float* __restrict__ bih_f, const float* __restrict__ bhh_f,
    const float* __restrict__ Wih_b, const float* __restrict__ Whh_b,
    const float* __restrict__ bih_b, const float* __restrict__ bhh_b,
    float* __restrict__ hsnap)         // (2, C, B, H)
{
    const int blk   = blockIdx.x;      // 0..3
    const int d     = blk >> 1;        // direction
    const int bbase = (blk & 1) << 4;  // batch half
    const int t  = threadIdx.x;        // 0..255
    const int w  = t >> 6;             // wave 0..3
    const int l  = t & 63;
    const int g  = l >> 4;             // k-group / D-row group
    const int la = l & 15;             // A-row within tile; also B col (batch)
    const int bg = bbase + la;         // global batch for this lane

    const float* __restrict__ Wih = d ? Wih_b : Wih_f;
    const float* __restrict__ Whh = d ? Whh_b : Whh_f;
    const float* __restrict__ bih = d ? bih_b : bih_f;
    const float* __restrict__ bhh = d ? bhh_b : bhh_f;

    __shared__ __align__(16) f16 hl[2][16][136];  // [buf][batch][k], +8 pad
    __shared__ float lds_pad[18432];              // 72KB inflation -> 1 blk/CU
    lds_pad[t] = 0.0f;                            // keep the array referenced

    // ---- A-fragments: 6 M-tiles (r0,r1,z0,z1,n0,n1) x 4 K-tiles ----
    const float* rR0 = Whh + ((size_t)(      32 * w + la)) * HH;
    const float* rR1 = rR0 + 16 * HH;
    const float* rZ0 = Whh + ((size_t)(128 + 32 * w + la)) * HH;
    const float* rZ1 = rZ0 + 16 * HH;
    const float* rN0 = Whh + ((size_t)(256 + 32 * w + la)) * HH;
    const float* rN1 = rN0 + 16 * HH;
    const int kb = 8 * g;
    f16x8 aR0k0 = packA8(rR0 + kb),      aR0k1 = packA8(rR0 + 32 + kb),
          aR0k2 = packA8(rR0 + 64 + kb), aR0k3 = packA8(rR0 + 96 + kb);
    f16x8 aR1k0 = packA8(rR1 + kb),      aR1k1 = packA8(rR1 + 32 + kb),
          aR1k2 = packA8(rR1 + 64 + kb), aR1k3 = packA8(rR1 + 96 + kb);
    f16x8 aZ0k0 = packA8(rZ0 + kb),      aZ0k1 = packA8(rZ0 + 32 + kb),
          aZ0k2 = packA8(rZ0 + 64 + kb), aZ0k3 = packA8(rZ0 + 96 + kb);
    f16x8 aZ1k0 = packA8(rZ1 + kb),      aZ1k1 = packA8(rZ1 + 32 + kb),
          aZ1k2 = packA8(rZ1 + 64 + kb), aZ1k3 = packA8(rZ1 + 96 + kb);
    f16x8 aN0k0 = packA8(rN0 + kb),      aN0k1 = packA8(rN0 + 32 + kb),
          aN0k2 = packA8(rN0 + 64 + kb), aN0k3 = packA8(rN0 + 96 + kb);
    f16x8 aN1k0 = packA8(rN1 + kb),      aN1k1 = packA8(rN1 + 32 + kb),
          aN1k2 = packA8(rN1 + 64 + kb), aN1k3 = packA8(rN1 + 96 + kb);
    asm volatile("" : "+v"(aR0k0), "+v"(aR0k1), "+v"(aR0k2), "+v"(aR0k3),
                      "+v"(aR1k0), "+v"(aR1k1), "+v"(aR1k2), "+v"(aR1k3),
                      "+v"(aZ0k0), "+v"(aZ0k1), "+v"(aZ0k2), "+v"(aZ0k3));
    asm volatile("" : "+v"(aZ1k0), "+v"(aZ1k1), "+v"(aZ1k2), "+v"(aZ1k3),
                      "+v"(aN0k0), "+v"(aN0k1), "+v"(aN0k2), "+v"(aN0k3),
                      "+v"(aN1k0), "+v"(aN1k1), "+v"(aN1k2), "+v"(aN1k3));

    // ---- Per-lane gate constants (D rows j0..j0+3 and j1..j1+3) ----
    const int j0 = 32 * w + 4 * g;
    const int j1 = j0 + 16;
    f32x4 wihr0 = *(const f32x4*)(Wih + j0);
    f32x4 wihr1 = *(const f32x4*)(Wih + j1);
    f32x4 wihz0 = *(const f32x4*)(Wih + HH + j0);
    f32x4 wihz1 = *(const f32x4*)(Wih + HH + j1);
    f32x4 wihn0 = *(const f32x4*)(Wih + 2 * HH + j0);
    f32x4 wihn1 = *(const f32x4*)(Wih + 2 * HH + j1);
    f32x4 seedr0 = *(const f32x4*)(bih + j0) + *(const f32x4*)(bhh + j0);
    f32x4 seedr1 = *(const f32x4*)(bih + j1) + *(const f32x4*)(bhh + j1);
    f32x4 seedz0 = *(const f32x4*)(bih + HH + j0) + *(const f32x4*)(bhh + HH + j0);
    f32x4 seedz1 = *(const f32x4*)(bih + HH + j1) + *(const f32x4*)(bhh + HH + j1);
    f32x4 seedn0 = *(const f32x4*)(bhh + 2 * HH + j0);
    f32x4 seedn1 = *(const f32x4*)(bhh + 2 * HH + j1);
    f32x4 bihn0  = *(const f32x4*)(bih + 2 * HH + j0);
    f32x4 bihn1  = *(const f32x4*)(bih + 2 * HH + j1);
    asm volatile("" : "+v"(wihr0), "+v"(wihr1), "+v"(wihz0), "+v"(wihz1),
                      "+v"(wihn0), "+v"(wihn1), "+v"(seedr0), "+v"(seedr1),
                      "+v"(seedz0), "+v"(seedz1), "+v"(seedn0), "+v"(seedn1),
                      "+v"(bihn0), "+v"(bihn1));

    // ---- h carry in f32 regs + f16 copy in LDS ----
    f32x4 hp0 = *(const f32x4*)(h_prev + ((size_t)d * BB + bg) * HH + j0);
    f32x4 hp1 = *(const f32x4*)(h_prev + ((size_t)d * BB + bg) * HH + j1);
    {
        u32x2 v0; v0.x = pack2f(hp0[0], hp0[1]); v0.y = pack2f(hp0[2], hp0[3]);
        u32x2 v1; v1.x = pack2f(hp1[0], hp1[1]); v1.y = pack2f(hp1[2], hp1[3]);
        *(u32x2*)&hl[0][la][j0] = v0;
        *(u32x2*)&hl[0][la][j1] = v1;
    }
    __syncthreads();

#define GSTEP(SRC, DST, TSS)                                                   \
    {                                                                          \
        const int tt = d ? (SS - 1 - (TSS)) : (TSS);                           \
        const float xv = x[((size_t)bg * SS + tt) * CC + cc];                  \
        const f16* hbase = &hl[SRC][la][8 * g];                                \
        const f16x8 b0 = *(const f16x8*)(hbase);                               \
        const f16x8 b1 = *(const f16x8*)(hbase + 32);                          \
        const f16x8 b2 = *(const f16x8*)(hbase + 64);                          \
        const f16x8 b3 = *(const f16x8*)(hbase + 96);                          \
        f32x4 cr0 = seedr0, cz0 = seedz0, cn0 = seedn0;                        \
        f32x4 cr1 = seedr1, cz1 = seedz1, cn1 = seedn1;                        \
        cr0 = MFMA16(aR0k0, b0, cr0); cr0 = MFMA16(aR0k1, b1, cr0);            \
        cr0 = MFMA16(aR0k2, b2, cr0); cr0 = MFMA16(aR0k3, b3, cr0);            \
        cz0 = MFMA16(aZ0k0, b0, cz0); cz0 = MFMA16(aZ0k1, b1, cz0);            \
        cz0 = MFMA16(aZ0k2, b2, cz0); cz0 = MFMA16(aZ0k3, b3, cz0);            \
        cn0 = MFMA16(aN0k0, b0, cn0); cn0 = MFMA16(aN0k1, b1, cn0);            \
        cn0 = MFMA16(aN0k2, b2, cn0); cn0 = MFMA16(aN0k3, b3, cn0);            \
        cr1 = MFMA16(aR1k0, b0, cr1); cr1 = MFMA16(aR1k1, b1, cr1);            \
        cr1 = MFMA16(aR1k2, b2, cr1); cr1 = MFMA16(aR1k3, b3, cr1);            \
        cz1 = MFMA16(aZ1k0, b0, cz1); cz1 = MFMA16(aZ1k1, b1, cz1);            \
        cz1 = MFMA16(aZ1k2, b2, cz1); cz1 = MFMA16(aZ1k3, b3, cz1);            \
        cn1 = MFMA16(aN1k0, b0, cn1); cn1 = MFMA16(aN1k1, b1, cn1);            \
        cn1 = MFMA16(aN1k2, b2, cn1); cn1 = MFMA16(aN1k3, b3, cn1);            \
        hp0 = gate4(cr0, cz0, cn0, wihr0, wihz0, wihn0, bihn0, xv, hp0);       \
        hp1 = gate4(cr1, cz1, cn1, wihr1, wihz1, wihn1, bihn1, xv, hp1);       \
        u32x2 o0; o0.x = pack2f(hp0[0], hp0[1]); o0.y = pack2f(hp0[2], hp0[3]);\
        u32x2 o1; o1.x = pack2f(hp1[0], hp1[1]); o1.y = pack2f(hp1[2], hp1[3]);\
        *(u32x2*)&hl[DST][la][j0] = o0;                                        \
        *(u32x2*)&hl[DST][la][j1] = o1;                                        \
        __syncthreads();                                                       \
    }

    for (int cc = 0; cc < CC; ++cc) {
        for (int ts = 0; ts < SS; ts += 2) {
            GSTEP(0, 1, ts)
            GSTEP(1, 0, ts + 1)
        }
        *(f32x4*)(hsnap + (((size_t)d * CC + cc) * BB + bg) * HH + j0) = hp0;
        *(f32x4*)(hsnap + (((size_t)d * CC + cc) * BB + bg) * HH + j1) = hp1;
    }
#undef GSTEP
}

// One block (= one wave of 64 threads) per (c,b): FC + ReLU + softmax over O=64.
__global__ __launch_bounds__(64) void fc_softmax_kernel(
    const float* __restrict__ hsnap,   // (2, C, B, H)
    const float* __restrict__ W_fc,    // (O, 2H)
    const float* __restrict__ b_fc,    // (O,)
    float* __restrict__ out)           // (B, C, O)
{
    const int cb = blockIdx.x;         // c * B + b
    const int c  = cb >> 5;
    const int b  = cb & 31;
    const int o  = threadIdx.x;        // 0..63

    __shared__ float feat[2 * HH];     // [hf, hb]
    #pragma unroll
    for (int i = 0; i < 4; ++i) {
        const int idx = i * 64 + o;            // 0..255
        const int dd  = idx >> 7;              // 0: hf, 1: hb
        const int jj  = idx & (HH - 1);
        feat[idx] = hsnap[(((size_t)dd * CC + c) * BB + b) * HH + jj];
    }
    __syncthreads();

    float acc = 0.f;
    const float4* wrow = reinterpret_cast<const float4*>(W_fc + o * 2 * HH);
    const float4* f4   = reinterpret_cast<const float4*>(feat);
    #pragma unroll
    for (int k = 0; k < 64; ++k) {
        const float4 wv = wrow[k];
        const float4 fv = f4[k];
        acc = fmaf(wv.x, fv.x, acc);
        acc = fmaf(wv.y, fv.y, acc);
        acc = fmaf(wv.z, fv.z, acc);
        acc = fmaf(wv.w, fv.w, acc);
    }
    float v = fmaxf(acc + b_fc[o], 0.0f);

    float m = v;
    #pragma unroll
    for (int off = 32; off; off >>= 1) m = fmaxf(m, __shfl_xor(m, off));
    const float e = __expf(v - m);
    float ssum = e;
    #pragma unroll
    for (int off = 32; off; off >>= 1) ssum += __shfl_xor(ssum, off);

    out[((size_t)b * CC + c) * OO + o] = e / ssum;
}

extern "C" void kernel_launch(void* const* d_in, const int* in_sizes, int n_in,
                              void* d_out, int out_size, void* d_ws, size_t ws_size,
                              hipStream_t stream) {
    const float* x      = (const float*)d_in[0];
    const float* h_prev = (const float*)d_in[1];
    const float* Wih_f  = (const float*)d_in[2];
    const float* Whh_f  = (const float*)d_in[3];
    const float* bih_f  = (const float*)d_in[4];
    const float* bhh_f  = (const float*)d_in[5];
    const float* Wih_b  = (const float*)d_in[6];
    const float* Whh_b  = (const float*)d_in[7];
    const float* bih_b  = (const float*)d_in[8];
    const float* bhh_b  = (const float*)d_in[9];
    const float* W_fc   = (const float*)d_in[10];
    const float* b_fc   = (const float*)d_in[11];
    float* out   = (float*)d_out;
    float* hsnap = (float*)d_ws;   // 2*C*B*H*4 = 4 MiB of scratch

    gru_chain_kernel<<<4, 256, 0, stream>>>(x, h_prev, Wih_f, Whh_f, bih_f, bhh_f,
                                            Wih_b, Whh_b, bih_b, bhh_b, hsnap);
    fc_softmax_kernel<<<CC * BB, 64, 0, stream>>>(hsnap, W_fc, b_fc, out);
}

// Round 15
// 15358.353 us; speedup vs baseline: 1.1973x; 1.1973x over previous
//
#include <hip/hip_runtime.h>
#include <hip/hip_bf16.h>

#define BB 32
#define SS 128
#define CC 128
#define HH 128
#define OO 64

typedef _Float16 f16;
typedef f16 h2 __attribute__((ext_vector_type(2)));
typedef f16 f16x8 __attribute__((ext_vector_type(8)));
typedef float f32x4 __attribute__((ext_vector_type(4)));
typedef unsigned u32x2 __attribute__((ext_vector_type(2)));
typedef unsigned u32x4 __attribute__((ext_vector_type(4)));

__device__ __forceinline__ float sigmoidf_(float x) {
    return 1.0f / (1.0f + __expf(-x));
}
__device__ __forceinline__ float tanh_fast_(float x) {
    return 1.0f - 2.0f / (__expf(2.0f * x) + 1.0f);
}
__device__ __forceinline__ unsigned pack2f(float a, float b) {
    h2 v; v[0] = (f16)a; v[1] = (f16)b;
    return __builtin_bit_cast(unsigned, v);
}
// 8 consecutive f32 -> f16x8. The k-slot bijection is ours as long as A-pack
// and B-layout agree (k = 8*(l>>4)+e within a K-tile) — R14 verified on HW.
__device__ __forceinline__ f16x8 packA8(const float* p) {
    u32x4 u;
    u.x = pack2f(p[0], p[1]); u.y = pack2f(p[2], p[3]);
    u.z = pack2f(p[4], p[5]); u.w = pack2f(p[6], p[7]);
    return __builtin_bit_cast(f16x8, u);
}
#define MFMA16(a, b, c) __builtin_amdgcn_mfma_f32_16x16x32_f16(a, b, c, 0, 0, 0)

// ROUND-15: R14's MFMA structure (numerically verified) with the latency
// items fixed. 8 waves (2/SIMD): wave w owns rows [16w,16w+16) for ALL 3
// gates -> 12 MFMA/wave + 4 gate outputs/lane (~70 VALU), half R14's
// per-wave tail, and a second wave per SIMD to fill stalls. x staged per
// column into LDS (burst of 2048 floats / 128 steps); xv = LDS broadcast.
// C/D layout (m89/R14-verified): col = lane&15 (batch), row = 4*(lane>>4)+e.
__global__
__attribute__((amdgpu_flat_work_group_size(512, 512), amdgpu_waves_per_eu(1, 2)))
void gru_chain_kernel(
    const float* __restrict__ x,       // (B,S,C)
    const float* __restrict__ h_prev,  // (2,B,H)
    const float* __restrict__ Wih_f, const float* __restrict__ Whh_f,
    const float* __restrict__ bih_f, const float* __restrict__ bhh_f,
    const float* __restrict__ Wih_b, const float* __restrict__ Whh_b,
    const float* __restrict__ bih_b, const float* __restrict__ bhh_b,
    float* __restrict__ hsnap)         // (2, C, B, H)
{
    const int blk   = blockIdx.x;      // 0..3
    const int d     = blk >> 1;        // direction
    const int bbase = (blk & 1) << 4;  // batch half
    const int t  = threadIdx.x;        // 0..511
    const int w  = t >> 6;             // wave 0..7
    const int l  = t & 63;
    const int g  = l >> 4;             // k-group / D-row group
    const int la = l & 15;             // A-row within tile; B col (batch)
    const int bg = bbase + la;         // global batch for this lane

    const float* __restrict__ Wih = d ? Wih_b : Wih_f;
    const float* __restrict__ Whh = d ? Whh_b : Whh_f;
    const float* __restrict__ bih = d ? bih_b : bih_f;
    const float* __restrict__ bhh = d ? bhh_b : bhh_f;

    __shared__ __align__(16) f16 hl[2][16][136];  // [buf][batch][k], +8 pad
    __shared__ float xcol[SS * 16];               // column stage [ts][batch], 8KB
    __shared__ float lds_pad[17408];              // 68KB inflation -> 1 blk/CU
    { volatile float* vp = lds_pad; vp[t] = 0.0f; }  // volatile: not DCE-able

    // ---- A-fragments: rows [16w,16w+16) x gates {r,z,n} x 4 K-tiles ----
    const float* rR = Whh + ((size_t)(      16 * w + la)) * HH;
    const float* rZ = Whh + ((size_t)(128 + 16 * w + la)) * HH;
    const float* rN = Whh + ((size_t)(256 + 16 * w + la)) * HH;
    const int kb = 8 * g;
    f16x8 aR0 = packA8(rR + kb),      aR1 = packA8(rR + 32 + kb),
          aR2 = packA8(rR + 64 + kb), aR3 = packA8(rR + 96 + kb);
    f16x8 aZ0 = packA8(rZ + kb),      aZ1 = packA8(rZ + 32 + kb),
          aZ2 = packA8(rZ + 64 + kb), aZ3 = packA8(rZ + 96 + kb);
    f16x8 aN0 = packA8(rN + kb),      aN1 = packA8(rN + 32 + kb),
          aN2 = packA8(rN + 64 + kb), aN3 = packA8(rN + 96 + kb);
    asm volatile("" : "+v"(aR0), "+v"(aR1), "+v"(aR2), "+v"(aR3),
                      "+v"(aZ0), "+v"(aZ1), "+v"(aZ2), "+v"(aZ3),
                      "+v"(aN0), "+v"(aN1), "+v"(aN2), "+v"(aN3));

    // ---- Per-lane gate constants (D rows j0..j0+3) ----
    const int j0 = 16 * w + 4 * g;
    f32x4 wihr = *(const f32x4*)(Wih + j0);
    f32x4 wihz = *(const f32x4*)(Wih + HH + j0);
    f32x4 wihn = *(const f32x4*)(Wih + 2 * HH + j0);
    f32x4 seedr = *(const f32x4*)(bih + j0) + *(const f32x4*)(bhh + j0);
    f32x4 seedz = *(const f32x4*)(bih + HH + j0) + *(const f32x4*)(bhh + HH + j0);
    f32x4 seedn = *(const f32x4*)(bhh + 2 * HH + j0);
    f32x4 bihn  = *(const f32x4*)(bih + 2 * HH + j0);
    asm volatile("" : "+v"(wihr), "+v"(wihz), "+v"(wihn), "+v"(seedr),
                      "+v"(seedz), "+v"(seedn), "+v"(bihn));

    // ---- h carry (f32 regs) + f16 copy in LDS ----
    f32x4 hp = *(const f32x4*)(h_prev + ((size_t)d * BB + bg) * HH + j0);
    {
        u32x2 v; v.x = pack2f(hp[0], hp[1]); v.y = pack2f(hp[2], hp[3]);
        *(u32x2*)&hl[0][la][j0] = v;
    }
    __syncthreads();

#define GSTEP(SRC, DST, TSS)                                                   \
    {                                                                          \
        const int tt = d ? (SS - 1 - (TSS)) : (TSS);                           \
        const float xv = xcol[tt * 16 + la];     /* LDS, conflict-free */      \
        const f16* hbase = &hl[SRC][la][8 * g];                                \
        const f16x8 b0 = *(const f16x8*)(hbase);                               \
        const f16x8 b1 = *(const f16x8*)(hbase + 32);                          \
        const f16x8 b2 = *(const f16x8*)(hbase + 64);                          \
        const f16x8 b3 = *(const f16x8*)(hbase + 96);                          \
        f32x4 cr = seedr, cz = seedz, cn = seedn;                              \
        cr = MFMA16(aR0, b0, cr); cr = MFMA16(aR1, b1, cr);                    \
        cr = MFMA16(aR2, b2, cr); cr = MFMA16(aR3, b3, cr);                    \
        cz = MFMA16(aZ0, b0, cz); cz = MFMA16(aZ1, b1, cz);                    \
        cz = MFMA16(aZ2, b2, cz); cz = MFMA16(aZ3, b3, cz);                    \
        cn = MFMA16(aN0, b0, cn); cn = MFMA16(aN1, b1, cn);                    \
        cn = MFMA16(aN2, b2, cn); cn = MFMA16(aN3, b3, cn);                    \
        _Pragma("unroll")                                                      \
        for (int e = 0; e < 4; ++e) {                                          \
            const float r   = sigmoidf_(fmaf(xv, wihr[e], cr[e]));             \
            const float z   = sigmoidf_(fmaf(xv, wihz[e], cz[e]));             \
            const float gin = fmaf(xv, wihn[e], bihn[e]);                      \
            const float n   = tanh_fast_(fmaf(r, cn[e], gin));                 \
            hp[e] = fmaf(z, hp[e] - n, n);       /* (1-z)*n + z*h */           \
        }                                                                      \
        u32x2 o; o.x = pack2f(hp[0], hp[1]); o.y = pack2f(hp[2], hp[3]);       \
        *(u32x2*)&hl[DST][la][j0] = o;                                         \
        __syncthreads();                                                       \
    }

    for (int cc = 0; cc < CC; ++cc) {
        // stage this column's x slice: 2048 floats, 4 per thread
        #pragma unroll
        for (int i = 0; i < 4; ++i) {
            const int e  = t + i * 512;          // 0..2047
            const int ts = e >> 4;
            const int bb = e & 15;
            xcol[e] = x[((size_t)(bbase + bb) * SS + ts) * CC + cc];
        }
        __syncthreads();
        for (int ts = 0; ts < SS; ts += 2) {
            GSTEP(0, 1, ts)
            GSTEP(1, 0, ts + 1)
        }
        *(f32x4*)(hsnap + (((size_t)d * CC + cc) * BB + bg) * HH + j0) = hp;
    }
#undef GSTEP
}

// One block (= one wave of 64 threads) per (c,b): FC + ReLU + softmax over O=64.
__global__ __launch_bounds__(64) void fc_softmax_kernel(
    const float* __restrict__ hsnap,   // (2, C, B, H)
    const float* __restrict__ W_fc,    // (O, 2H)
    const float* __restrict__ b_fc,    // (O,)
    float* __restrict__ out)           // (B, C, O)
{
    const int cb = blockIdx.x;         // c * B + b
    const int c  = cb >> 5;
    const int b  = cb & 31;
    const int o  = threadIdx.x;        // 0..63

    __shared__ float feat[2 * HH];     // [hf, hb]
    #pragma unroll
    for (int i = 0; i < 4; ++i) {
        const int idx = i * 64 + o;            // 0..255
        const int dd  = idx >> 7;              // 0: hf, 1: hb
        const int jj  = idx & (HH - 1);
        feat[idx] = hsnap[(((size_t)dd * CC + c) * BB + b) * HH + jj];
    }
    __syncthreads();

    float acc = 0.f;
    const float4* wrow = reinterpret_cast<const float4*>(W_fc + o * 2 * HH);
    const float4* f4   = reinterpret_cast<const float4*>(feat);
    #pragma unroll
    for (int k = 0; k < 64; ++k) {
        const float4 wv = wrow[k];
        const float4 fv = f4[k];
        acc = fmaf(wv.x, fv.x, acc);
        acc = fmaf(wv.y, fv.y, acc);
        acc = fmaf(wv.z, fv.z, acc);
        acc = fmaf(wv.w, fv.w, acc);
    }
    float v = fmaxf(acc + b_fc[o], 0.0f);

    float m = v;
    #pragma unroll
    for (int off = 32; off; off >>= 1) m = fmaxf(m, __shfl_xor(m, off));
    const float e = __expf(v - m);
    float ssum = e;
    #pragma unroll
    for (int off = 32; off; off >>= 1) ssum += __shfl_xor(ssum, off);

    out[((size_t)b * CC + c) * OO + o] = e / ssum;
}

extern "C" void kernel_launch(void* const* d_in, const int* in_sizes, int n_in,
                              void* d_out, int out_size, void* d_ws, size_t ws_size,
                              hipStream_t stream) {
    const float* x      = (const float*)d_in[0];
    const float* h_prev = (const float*)d_in[1];
    const float* Wih_f  = (const float*)d_in[2];
    const float* Whh_f  = (const float*)d_in[3];
    const float* bih_f  = (const float*)d_in[4];
    const float* bhh_f  = (const float*)d_in[5];
    const float* Wih_b  = (const float*)d_in[6];
    const float* Whh_b  = (const float*)d_in[7];
    const float* bih_b  = (const float*)d_in[8];
    const float* bhh_b  = (const float*)d_in[9];
    const float* W_fc   = (const float*)d_in[10];
    const float* b_fc   = (const float*)d_in[11];
    float* out   = (float*)d_out;
    float* hsnap = (float*)d_ws;   // 2*C*B*H*4 = 4 MiB of scratch

    gru_chain_kernel<<<4, 512, 0, stream>>>(x, h_prev, Wih_f, Whh_f, bih_f, bhh_f,
                                            Wih_b, Whh_b, bih_b, bhh_b, hsnap);
    fc_softmax_kernel<<<CC * BB, 64, 0, stream>>>(hsnap, W_fc, b_fc, out);
}